// Round 10
// baseline (273.837 us; speedup 1.0000x reference)
//
#include <hip/hip_runtime.h>
#include <hip/hip_bf16.h>

#define SEQ   2048
#define BATCH 2
#define NHEAD 16
#define HDIM  64
#define CDIM  1024
#define QKV_F 5120
#define SCALE 0.125f
#define LOG2E 1.44269504f
#define EPSV  1e-5f

typedef __bf16 bf16;
typedef __bf16 bf16x4 __attribute__((ext_vector_type(4)));
typedef __bf16 bf16x8 __attribute__((ext_vector_type(8)));
typedef float  f32x4  __attribute__((ext_vector_type(4)));

#define MFMA16(a, b, c) __builtin_amdgcn_mfma_f32_16x16x32_bf16(a, b, c, 0, 0, 0)

__device__ __forceinline__ unsigned pkbf(float a, float b) {
    union { bf16 h[2]; unsigned u; } t;
    t.h[0] = (bf16)a; t.h[1] = (bf16)b;
    return t.u;
}
__device__ __forceinline__ unsigned short bfbits(float a) {
    union { bf16 h; unsigned short u; } t;
    t.h = (bf16)a;
    return t.u;
}
__device__ __forceinline__ void gload16(const void* g, void* l) {
    __builtin_amdgcn_global_load_lds(
        (const __attribute__((address_space(1))) unsigned int*)g,
        (__attribute__((address_space(3))) unsigned int*)l, 16, 0, 0);
}

// ---------------------------------------------------------------------------
// f32 -> bf16 convert, 8 elems/thread.
// ---------------------------------------------------------------------------
__global__ __launch_bounds__(256) void cvt_bf16(
    const float* __restrict__ s, bf16* __restrict__ d)
{
    const int i = (blockIdx.x * 256 + threadIdx.x) * 8;
    float4 a = *(const float4*)(s + i);
    float4 b = *(const float4*)(s + i + 4);
    bf16x8 t;
    t[0] = (bf16)a.x; t[1] = (bf16)a.y; t[2] = (bf16)a.z; t[3] = (bf16)a.w;
    t[4] = (bf16)b.x; t[5] = (bf16)b.y; t[6] = (bf16)b.z; t[7] = (bf16)b.w;
    *(bf16x8*)(d + i) = t;
}

// ---------------------------------------------------------------------------
// m97-structure GEMM: C = A(MxK) * B(NnxK)^T, bf16 in, global_load_lds x16.
// EPI 0: scatter qkv (q1/q2 scaled by SCALE*LOG2E); V transposed [d][n] with
//        the attention PV token-run permutation baked in.
// EPI 1: fp32 + bias.
// ---------------------------------------------------------------------------
template <int EPI>
__global__ __launch_bounds__(256) void gemm_lds(
    const bf16* __restrict__ A, const bf16* __restrict__ Bw,
    const float* __restrict__ bias,
    bf16* __restrict__ outq, float* __restrict__ outp,
    int M, int Nn, int K)
{
    __shared__ __align__(16) bf16 As[128 * 64];
    __shared__ __align__(16) bf16 Bs[128 * 64];

    const int tid  = threadIdx.x;
    const int lane = tid & 63;
    const int wave = tid >> 6;
    const int wr = wave >> 1, wc = wave & 1;
    const int g = lane >> 4, fr = lane & 15;
    const int m0 = blockIdx.y * 128;
    const int n0 = blockIdx.x * 128;

    const int lrow = lane >> 3;
    const int lcol = (lane & 7) << 3;

    f32x4 acc[4][4];
#pragma unroll
    for (int m = 0; m < 4; ++m)
#pragma unroll
        for (int n = 0; n < 4; ++n) acc[m][n] = f32x4{0.f, 0.f, 0.f, 0.f};

    const int nkt = K >> 6;
    for (int kt = 0; kt < nkt; ++kt) {
        const int k0 = kt << 6;
        __syncthreads();
#pragma unroll
        for (int i = 0; i < 4; ++i) {
            const int chunk = wave * 4 + i;
            const int row = chunk * 8 + lrow;
            gload16(A + (size_t)(m0 + row) * K + k0 + lcol, As + chunk * 512);
            gload16(Bw + (size_t)(n0 + row) * K + k0 + lcol, Bs + chunk * 512);
        }
        __syncthreads();
#pragma unroll
        for (int ks = 0; ks < 2; ++ks) {
            bf16x8 af[4], bfr[4];
#pragma unroll
            for (int m = 0; m < 4; ++m)
                af[m] = *(const bf16x8*)(As + (wr * 64 + m * 16 + fr) * 64 + ks * 32 + g * 8);
#pragma unroll
            for (int n = 0; n < 4; ++n)
                bfr[n] = *(const bf16x8*)(Bs + (wc * 64 + n * 16 + fr) * 64 + ks * 32 + g * 8);
#pragma unroll
            for (int m = 0; m < 4; ++m)
#pragma unroll
                for (int n = 0; n < 4; ++n)
                    acc[m][n] = MFMA16(af[m], bfr[n], acc[m][n]);
        }
    }

#pragma unroll
    for (int m = 0; m < 4; ++m) {
#pragma unroll
        for (int n = 0; n < 4; ++n) {
            const int row0 = m0 + wr * 64 + m * 16 + g * 4;
            const int col  = n0 + wc * 64 + n * 16 + fr;
            if (EPI == 0) {
                const int bb = row0 >> 11, nn = row0 & (SEQ - 1);
                const int sI = col >> 10, rem = col & (CDIM - 1);
                const int hh = rem >> 6, dd = rem & 63;
                const size_t base = ((size_t)((sI * BATCH + bb) * NHEAD + hh)) << 17;
                if (sI == 4) {
                    // V^T [d][n] with 4-token-run permutation within 64-tiles
                    const int t4 = (nn >> 2) & 15;
                    const int G = t4 >> 3, jh = (t4 >> 2) & 1, gg = t4 & 3;
                    const int u = (G << 3) | (gg << 1) | jh;
                    const int nnp = (nn & ~63) | (u << 2);
                    ushort4 uu;
                    uu.x = bfbits(acc[m][n][0]);
                    uu.y = bfbits(acc[m][n][1]);
                    uu.z = bfbits(acc[m][n][2]);
                    uu.w = bfbits(acc[m][n][3]);
                    *(ushort4*)(outq + base + ((size_t)dd << 11) + nnp) = uu;
                } else {
                    const float sc = (sI < 2) ? SCALE * LOG2E : 1.f;
#pragma unroll
                    for (int r = 0; r < 4; ++r)
                        outq[base + ((size_t)(nn + r) << 6) + dd] = (bf16)(acc[m][n][r] * sc);
                }
            } else {
#pragma unroll
                for (int r = 0; r < 4; ++r)
                    outp[(size_t)(row0 + r) * Nn + col] = acc[m][n][r] + bias[col];
            }
        }
    }
}

// ---------------------------------------------------------------------------
// Differential flash attention: R5 inner loop (16 q/wave, per-state softmax,
// full gload16 staging, permuted V) + KV-split across 2 groups of 4 waves.
// Block = 8 waves: group grp handles kv half [grp*1024, +1024) for the same
// 64 q-rows; partials (m,l,o) merged via LDS at the end.
// grid = (BH=32, SEQ/64=32) -> 8192 waves; LDS 48KB -> up to 3 blocks/CU.
// launch_bounds(512,2): VGPR budget 256 -> NO spill (R9's (512,4) forced a
// 64-VGPR cap -> 50-reg spill -> WRITE_SIZE 67MB; that was the regression).
// ---------------------------------------------------------------------------
__global__ __launch_bounds__(512, 2) void diff_attn(
    const bf16* __restrict__ qkv,
    const float* __restrict__ lq1, const float* __restrict__ lk1,
    const float* __restrict__ lq2, const float* __restrict__ lk2,
    float* __restrict__ attn_out)
{
    __shared__ __align__(16) char SM[49152];    // [grp][K1|K2|Vt] 24KB each

    const int tid = threadIdx.x;
    const int lane = tid & 63, wave = tid >> 6;     // 0..7
    const int wg = wave & 3, grp = wave >> 2;
    const int g = lane >> 4, fr = lane & 15;
    const int bh = blockIdx.x, b = bh >> 4, h = bh & 15;
    const int q0 = blockIdx.y * 64 + wg * 16;
    const int kv0 = grp * (SEQ / 2);

    float ls1 = 0.f, ls2 = 0.f;
    for (int i = 0; i < HDIM; ++i) { ls1 += lq1[i] * lk1[i]; ls2 += lq2[i] * lk2[i]; }
    const float lam = __expf(ls1) - __expf(ls2) + 0.8f;

    const size_t HS = (size_t)SEQ * HDIM;
    const char* q1p = (const char*)(qkv + ((size_t)((0 * BATCH + b) * NHEAD + h)) * HS);
    const char* q2p = (const char*)(qkv + ((size_t)((1 * BATCH + b) * NHEAD + h)) * HS);
    const char* k1p = (const char*)(qkv + ((size_t)((2 * BATCH + b) * NHEAD + h)) * HS);
    const char* k2p = (const char*)(qkv + ((size_t)((3 * BATCH + b) * NHEAD + h)) * HS);
    const char* vtp = (const char*)(qkv + ((size_t)((4 * BATCH + b) * NHEAD + h)) * HS);

    bf16x8 qf1[2], qf2[2];
#pragma unroll
    for (int ks = 0; ks < 2; ++ks) {
        qf1[ks] = *(const bf16x8*)(q1p + (size_t)(q0 + fr) * 128 + ks * 64 + g * 16);
        qf2[ks] = *(const bf16x8*)(q2p + (size_t)(q0 + fr) * 128 + ks * 64 + g * 16);
    }

    const f32x4 z4{0.f, 0.f, 0.f, 0.f};
    f32x4 o1[4], o2[4];
#pragma unroll
    for (int d = 0; d < 4; ++d) { o1[d] = z4; o2[d] = z4; }
    f32x4 l1v = z4, l2v = z4;
    float m1 = -1e30f, m2 = -1e30f;

    const int lrow8 = lane >> 3;
    const int scol  = ((lane & 7) ^ lrow8) << 4;
    const int xw    = (fr & 7) << 4;

    char* base = SM + grp * 24576;
    const char* K1s = base;
    const char* K2s = base + 8192;
    const char* Vts = base + 16384;

    auto smax = [&](f32x4& s0, f32x4& s1, f32x4& s2, f32x4& s3,
                    float& mS, f32x4& lv, f32x4* o, unsigned* pw) {
        f32x4 t = __builtin_elementwise_max(
            __builtin_elementwise_max(s0, s1), __builtin_elementwise_max(s2, s3));
        float pm = fmaxf(fmaxf(t[0], t[1]), fmaxf(t[2], t[3]));
        pm = fmaxf(pm, __shfl_xor(pm, 16));
        pm = fmaxf(pm, __shfl_xor(pm, 32));
        if (!__all(pm <= mS + 8.f * LOG2E)) {   // defer-max
            float mn = fmaxf(mS, pm);
            float alpha = __builtin_amdgcn_exp2f(mS - mn);
            lv *= alpha;
#pragma unroll
            for (int d = 0; d < 4; ++d) o[d] *= alpha;
            mS = mn;
        }
#pragma unroll
        for (int r = 0; r < 4; ++r) {
            s0[r] = __builtin_amdgcn_exp2f(s0[r] - mS);
            s1[r] = __builtin_amdgcn_exp2f(s1[r] - mS);
            s2[r] = __builtin_amdgcn_exp2f(s2[r] - mS);
            s3[r] = __builtin_amdgcn_exp2f(s3[r] - mS);
        }
        lv += (s0 + s1) + (s2 + s3);
        pw[0] = pkbf(s0[0], s0[1]); pw[1] = pkbf(s0[2], s0[3]);
        pw[2] = pkbf(s1[0], s1[1]); pw[3] = pkbf(s1[2], s1[3]);
        pw[4] = pkbf(s2[0], s2[1]); pw[5] = pkbf(s2[2], s2[3]);
        pw[6] = pkbf(s3[0], s3[1]); pw[7] = pkbf(s3[2], s3[3]);
    };

#define KRD(Ks, n, ks) (*(const bf16x8*)((Ks) + ((n) * 16 + fr) * 128 + (((ks) * 64 + g * 16) ^ xw)))

    for (int kt = 0; kt < SEQ / 2 / 64; ++kt) {
        const int kvb = kv0 + kt * 64;
        __syncthreads();
        // group stages its 24 chunks of 1024B; wave takes 6
#pragma unroll
        for (int i = 0; i < 6; ++i) {
            const int c = wg * 6 + i;
            const int t = c >> 3, ch = c & 7;
            const int row = ch * 8 + lrow8;
            char* ldst = base + t * 8192 + ch * 1024;
            const char* src;
            if (t == 0)      src = k1p + (size_t)(kvb + row) * 128 + scol;
            else if (t == 1) src = k2p + (size_t)(kvb + row) * 128 + scol;
            else             src = vtp + (size_t)row * (SEQ * 2) + (size_t)kvb * 2 + scol;
            gload16(src, ldst);
        }
        __syncthreads();

        // ---- QK state 1 ----
        f32x4 s10, s11, s12, s13;
        __builtin_amdgcn_s_setprio(1);
        s10 = MFMA16(KRD(K1s, 0, 0), qf1[0], z4);
        s11 = MFMA16(KRD(K1s, 1, 0), qf1[0], z4);
        s12 = MFMA16(KRD(K1s, 2, 0), qf1[0], z4);
        s13 = MFMA16(KRD(K1s, 3, 0), qf1[0], z4);
        s10 = MFMA16(KRD(K1s, 0, 1), qf1[1], s10);
        s11 = MFMA16(KRD(K1s, 1, 1), qf1[1], s11);
        s12 = MFMA16(KRD(K1s, 2, 1), qf1[1], s12);
        s13 = MFMA16(KRD(K1s, 3, 1), qf1[1], s13);
        __builtin_amdgcn_s_setprio(0);
        unsigned p1w[8];
        smax(s10, s11, s12, s13, m1, l1v, o1, p1w);

        // ---- QK state 2 (MFMAs overlap state-1 softmax VALU) ----
        f32x4 s20, s21, s22, s23;
        __builtin_amdgcn_s_setprio(1);
        s20 = MFMA16(KRD(K2s, 0, 0), qf2[0], z4);
        s21 = MFMA16(KRD(K2s, 1, 0), qf2[0], z4);
        s22 = MFMA16(KRD(K2s, 2, 0), qf2[0], z4);
        s23 = MFMA16(KRD(K2s, 3, 0), qf2[0], z4);
        s20 = MFMA16(KRD(K2s, 0, 1), qf2[1], s20);
        s21 = MFMA16(KRD(K2s, 1, 1), qf2[1], s21);
        s22 = MFMA16(KRD(K2s, 2, 1), qf2[1], s22);
        s23 = MFMA16(KRD(K2s, 3, 1), qf2[1], s23);
        __builtin_amdgcn_s_setprio(0);
        unsigned p2w[8];
        smax(s20, s21, s22, s23, m2, l2v, o2, p2w);

        // ---- PV, both states (shared V fragments) ----
        __builtin_amdgcn_s_setprio(1);
#pragma unroll
        for (int G = 0; G < 2; ++G) {
            union { unsigned u[4]; bf16x8 v; } pf1, pf2;
#pragma unroll
            for (int w = 0; w < 4; ++w) { pf1.u[w] = p1w[G * 4 + w]; pf2.u[w] = p2w[G * 4 + w]; }
#pragma unroll
            for (int ds = 0; ds < 4; ++ds) {
                const int vrow = ds * 16 + fr;
                bf16x8 vf = *(const bf16x8*)(Vts + vrow * 128 +
                              ((G * 64 + g * 16) ^ ((vrow & 7) << 4)));
                o1[ds] = MFMA16(vf, pf1.v, o1[ds]);
                o2[ds] = MFMA16(vf, pf2.v, o2[ds]);
            }
        }
        __builtin_amdgcn_s_setprio(0);
    }
#undef KRD

    // ---- reduce l to scalars (per q, replicated across g-lanes) ----
    float l1 = (l1v[0] + l1v[1]) + (l1v[2] + l1v[3]);
    float l2 = (l2v[0] + l2v[1]) + (l2v[2] + l2v[3]);
    l1 += __shfl_xor(l1, 16); l1 += __shfl_xor(l1, 32);
    l2 += __shfl_xor(l2, 16); l2 += __shfl_xor(l2, 32);

    // ---- merge the two kv halves via LDS ----
    float* MF = (float*)SM;              // 4 planes x 256
    float* OF = (float*)(SM + 4096);     // 32 planes x 256
    __syncthreads();
    if (grp == 1) {
        const int p = tid - 256;
        MF[0 * 256 + p] = m1; MF[1 * 256 + p] = l1;
        MF[2 * 256 + p] = m2; MF[3 * 256 + p] = l2;
#pragma unroll
        for (int ds = 0; ds < 4; ++ds)
#pragma unroll
            for (int r = 0; r < 4; ++r) {
                OF[(ds * 4 + r) * 256 + p]        = o1[ds][r];
                OF[(16 + ds * 4 + r) * 256 + p]   = o2[ds][r];
            }
    }
    __syncthreads();
    if (grp == 0) {
        const float mB1 = MF[0 * 256 + tid], lB1 = MF[1 * 256 + tid];
        const float mB2 = MF[2 * 256 + tid], lB2 = MF[3 * 256 + tid];
        const float mn1 = fmaxf(m1, mB1), mn2 = fmaxf(m2, mB2);
        const float aA1 = __builtin_amdgcn_exp2f(m1 - mn1);
        const float aB1 = __builtin_amdgcn_exp2f(mB1 - mn1);
        const float aA2 = __builtin_amdgcn_exp2f(m2 - mn2);
        const float aB2 = __builtin_amdgcn_exp2f(mB2 - mn2);
        const float L1 = l1 * aA1 + lB1 * aB1;
        const float L2 = l2 * aA2 + lB2 * aB2;
        const float i1 = 1.f / L1;
        const float i2 = lam / L2;
        float* op = attn_out + ((size_t)(b * SEQ + q0 + fr)) * CDIM + h * HDIM;
#pragma unroll
        for (int ds = 0; ds < 4; ++ds) {
            float4 o;
#pragma unroll
            for (int r = 0; r < 4; ++r) {
                const float v1 = o1[ds][r] * aA1 + OF[(ds * 4 + r) * 256 + tid] * aB1;
                const float v2 = o2[ds][r] * aA2 + OF[(16 + ds * 4 + r) * 256 + tid] * aB2;
                ((float*)&o)[r] = v1 * i1 - i2 * v2;
            }
            *(float4*)(op + ds * 16 + g * 4) = o;
        }
    }
}

// ---------------------------------------------------------------------------
// RMSNorm over last dim (1024) + 0.2 scale, fp32 in -> bf16 out.
// ---------------------------------------------------------------------------
__global__ __launch_bounds__(256) void rmsnorm_bf16(
    const float* __restrict__ in, bf16* __restrict__ out)
{
    __shared__ float red[4];
    const int row = blockIdx.x, tid = threadIdx.x;
    const float4 v = ((const float4*)(in + (size_t)row * CDIM))[tid];
    float ss = v.x * v.x + v.y * v.y + v.z * v.z + v.w * v.w;
#pragma unroll
    for (int m = 1; m < 64; m <<= 1) ss += __shfl_xor(ss, m);
    if ((tid & 63) == 0) red[tid >> 6] = ss;
    __syncthreads();
    float tot = red[0] + red[1] + red[2] + red[3];
    float sc = rsqrtf(tot * (1.f / CDIM) + EPSV) * 0.2f;
    bf16x4 o;
    o[0] = (bf16)(v.x * sc); o[1] = (bf16)(v.y * sc);
    o[2] = (bf16)(v.z * sc); o[3] = (bf16)(v.w * sc);
    ((bf16x4*)(out + (size_t)row * CDIM))[tid] = o;
}

extern "C" void kernel_launch(void* const* d_in, const int* in_sizes, int n_in,
                              void* d_out, int out_size, void* d_ws, size_t ws_size,
                              hipStream_t stream)
{
    (void)in_sizes; (void)n_in; (void)out_size; (void)ws_size;
    const float* x      = (const float*)d_in[0];
    const float* qkv_w  = (const float*)d_in[1];
    const float* proj_w = (const float*)d_in[2];
    const float* proj_b = (const float*)d_in[3];
    const float* lq1    = (const float*)d_in[4];
    const float* lk1    = (const float*)d_in[5];
    const float* lq2    = (const float*)d_in[6];
    const float* lk2    = (const float*)d_in[7];
    float* out = (float*)d_out;

    char* ws = (char*)d_ws;
    bf16*  qkv_t    = (bf16*)ws;
    bf16*  attn_b   = (bf16*)ws;
    float* attn_out = (float*)(ws + (size_t)40 * 1024 * 1024);
    bf16*  x_b      = (bf16*)(ws + (size_t)40 * 1024 * 1024);
    bf16*  qkvw_b   = (bf16*)(ws + (size_t)56 * 1024 * 1024);
    bf16*  projw_b  = (bf16*)(ws + (size_t)66 * 1024 * 1024);

    dim3 blk(256);
    cvt_bf16<<<dim3((BATCH * SEQ * CDIM) / 2048), blk, 0, stream>>>(x, x_b);
    cvt_bf16<<<dim3((QKV_F * CDIM) / 2048), blk, 0, stream>>>(qkv_w, qkvw_b);
    cvt_bf16<<<dim3((CDIM * CDIM) / 2048), blk, 0, stream>>>(proj_w, projw_b);
    gemm_lds<0><<<dim3(QKV_F / 128, (BATCH * SEQ) / 128), blk, 0, stream>>>(
        x_b, qkvw_b, nullptr, qkv_t, nullptr, BATCH * SEQ, QKV_F, CDIM);
    diff_attn<<<dim3(BATCH * NHEAD, SEQ / 64), dim3(512), 0, stream>>>(
        qkv_t, lq1, lk1, lq2, lk2, attn_out);
    rmsnorm_bf16<<<dim3(BATCH * SEQ), blk, 0, stream>>>(attn_out, attn_b);
    gemm_lds<1><<<dim3(CDIM / 128, (BATCH * SEQ) / 128), blk, 0, stream>>>(
        attn_b, projw_b, proj_b, nullptr, out, BATCH * SEQ, CDIM, CDIM);
}

// Round 11
// 244.039 us; speedup vs baseline: 1.1221x; 1.1221x over previous
//
#include <hip/hip_runtime.h>
#include <hip/hip_bf16.h>

#define SEQ   2048
#define BATCH 2
#define NHEAD 16
#define HDIM  64
#define CDIM  1024
#define QKV_F 5120
#define SCALE 0.125f
#define LOG2E 1.44269504f
#define EPSV  1e-5f

typedef __bf16 bf16;
typedef __bf16 bf16x4 __attribute__((ext_vector_type(4)));
typedef __bf16 bf16x8 __attribute__((ext_vector_type(8)));
typedef float  f32x4  __attribute__((ext_vector_type(4)));

#define MFMA16(a, b, c) __builtin_amdgcn_mfma_f32_16x16x32_bf16(a, b, c, 0, 0, 0)

__device__ __forceinline__ unsigned pkbf(float a, float b) {
    union { bf16 h[2]; unsigned u; } t;
    t.h[0] = (bf16)a; t.h[1] = (bf16)b;
    return t.u;
}
__device__ __forceinline__ unsigned short bfbits(float a) {
    union { bf16 h; unsigned short u; } t;
    t.h = (bf16)a;
    return t.u;
}
__device__ __forceinline__ void gload16(const void* g, void* l) {
    __builtin_amdgcn_global_load_lds(
        (const __attribute__((address_space(1))) unsigned int*)g,
        (__attribute__((address_space(3))) unsigned int*)l, 16, 0, 0);
}

// ---------------------------------------------------------------------------
// Merged f32 -> bf16 convert for x (2048 blk), qkv_w (2560 blk), proj_w (512).
// 8 elems/thread, 2048 elems/block. grid = 5120.
// ---------------------------------------------------------------------------
__global__ __launch_bounds__(256) void cvt_all(
    const float* __restrict__ x,  bf16* __restrict__ xb,
    const float* __restrict__ qw, bf16* __restrict__ qwb,
    const float* __restrict__ pw, bf16* __restrict__ pwb)
{
    const int bid = blockIdx.x;
    const float* s;
    bf16* d;
    int off;
    if (bid < 2048)      { s = x;  d = xb;  off = bid; }
    else if (bid < 4608) { s = qw; d = qwb; off = bid - 2048; }
    else                 { s = pw; d = pwb; off = bid - 4608; }
    const int i = (off * 256 + threadIdx.x) * 8;
    float4 a = *(const float4*)(s + i);
    float4 b = *(const float4*)(s + i + 4);
    bf16x8 t;
    t[0] = (bf16)a.x; t[1] = (bf16)a.y; t[2] = (bf16)a.z; t[3] = (bf16)a.w;
    t[4] = (bf16)b.x; t[5] = (bf16)b.y; t[6] = (bf16)b.z; t[7] = (bf16)b.w;
    *(bf16x8*)(d + i) = t;
}

// ---------------------------------------------------------------------------
// m97-structure GEMM: C = A(MxK) * B(NnxK)^T, bf16 in, global_load_lds x16.
// EPI 0: scatter qkv (q1/q2 scaled by SCALE*LOG2E); V transposed [d][n] with
//        the attention PV token-run permutation baked in.
// EPI 1: fp32 + bias.
// ---------------------------------------------------------------------------
template <int EPI>
__global__ __launch_bounds__(256) void gemm_lds(
    const bf16* __restrict__ A, const bf16* __restrict__ Bw,
    const float* __restrict__ bias,
    bf16* __restrict__ outq, float* __restrict__ outp,
    int M, int Nn, int K)
{
    __shared__ __align__(16) bf16 As[128 * 64];
    __shared__ __align__(16) bf16 Bs[128 * 64];

    const int tid  = threadIdx.x;
    const int lane = tid & 63;
    const int wave = tid >> 6;
    const int wr = wave >> 1, wc = wave & 1;
    const int g = lane >> 4, fr = lane & 15;
    const int m0 = blockIdx.y * 128;
    const int n0 = blockIdx.x * 128;

    const int lrow = lane >> 3;
    const int lcol = (lane & 7) << 3;

    f32x4 acc[4][4];
#pragma unroll
    for (int m = 0; m < 4; ++m)
#pragma unroll
        for (int n = 0; n < 4; ++n) acc[m][n] = f32x4{0.f, 0.f, 0.f, 0.f};

    const int nkt = K >> 6;
    for (int kt = 0; kt < nkt; ++kt) {
        const int k0 = kt << 6;
        __syncthreads();
#pragma unroll
        for (int i = 0; i < 4; ++i) {
            const int chunk = wave * 4 + i;
            const int row = chunk * 8 + lrow;
            gload16(A + (size_t)(m0 + row) * K + k0 + lcol, As + chunk * 512);
            gload16(Bw + (size_t)(n0 + row) * K + k0 + lcol, Bs + chunk * 512);
        }
        __syncthreads();
#pragma unroll
        for (int ks = 0; ks < 2; ++ks) {
            bf16x8 af[4], bfr[4];
#pragma unroll
            for (int m = 0; m < 4; ++m)
                af[m] = *(const bf16x8*)(As + (wr * 64 + m * 16 + fr) * 64 + ks * 32 + g * 8);
#pragma unroll
            for (int n = 0; n < 4; ++n)
                bfr[n] = *(const bf16x8*)(Bs + (wc * 64 + n * 16 + fr) * 64 + ks * 32 + g * 8);
#pragma unroll
            for (int m = 0; m < 4; ++m)
#pragma unroll
                for (int n = 0; n < 4; ++n)
                    acc[m][n] = MFMA16(af[m], bfr[n], acc[m][n]);
        }
    }

#pragma unroll
    for (int m = 0; m < 4; ++m) {
#pragma unroll
        for (int n = 0; n < 4; ++n) {
            const int row0 = m0 + wr * 64 + m * 16 + g * 4;
            const int col  = n0 + wc * 64 + n * 16 + fr;
            if (EPI == 0) {
                const int bb = row0 >> 11, nn = row0 & (SEQ - 1);
                const int sI = col >> 10, rem = col & (CDIM - 1);
                const int hh = rem >> 6, dd = rem & 63;
                const size_t base = ((size_t)((sI * BATCH + bb) * NHEAD + hh)) << 17;
                if (sI == 4) {
                    // V^T [d][n] with 4-token-run permutation within 64-tiles
                    const int t4 = (nn >> 2) & 15;
                    const int G = t4 >> 3, jh = (t4 >> 2) & 1, gg = t4 & 3;
                    const int u = (G << 3) | (gg << 1) | jh;
                    const int nnp = (nn & ~63) | (u << 2);
                    ushort4 uu;
                    uu.x = bfbits(acc[m][n][0]);
                    uu.y = bfbits(acc[m][n][1]);
                    uu.z = bfbits(acc[m][n][2]);
                    uu.w = bfbits(acc[m][n][3]);
                    *(ushort4*)(outq + base + ((size_t)dd << 11) + nnp) = uu;
                } else {
                    const float sc = (sI < 2) ? SCALE * LOG2E : 1.f;
#pragma unroll
                    for (int r = 0; r < 4; ++r)
                        outq[base + ((size_t)(nn + r) << 6) + dd] = (bf16)(acc[m][n][r] * sc);
                }
            } else {
#pragma unroll
                for (int r = 0; r < 4; ++r)
                    outp[(size_t)(row0 + r) * Nn + col] = acc[m][n][r] + bias[col];
            }
        }
    }
}

// ---------------------------------------------------------------------------
// Differential flash attention — best-known structure (R5 skeleton):
// 4 waves x 16 q = 64 q/block, 24KB single LDS buffer, 4 blocks/CU,
// PER-STATE softmax (shared-max was R7's regression), full global_load_lds
// staging for K1/K2/V with pre-swizzled source (zero bank conflicts),
// V kv-permuted in the global layout so the PV P-fragment is lane-local.
// grid = (BH=32, SEQ/64=32).
// ---------------------------------------------------------------------------
__global__ __launch_bounds__(256, 4) void diff_attn(
    const bf16* __restrict__ qkv,
    const float* __restrict__ lq1, const float* __restrict__ lk1,
    const float* __restrict__ lq2, const float* __restrict__ lk2,
    float* __restrict__ attn_out)
{
    __shared__ __align__(16) char SM[24576];    // K1 | K2 | Vt, 8 KB each

    const int tid = threadIdx.x;
    const int lane = tid & 63, wave = tid >> 6;
    const int g = lane >> 4, fr = lane & 15;
    const int bh = blockIdx.x, b = bh >> 4, h = bh & 15;
    const int q0 = blockIdx.y * 64 + wave * 16;

    float ls1 = 0.f, ls2 = 0.f;
    for (int i = 0; i < HDIM; ++i) { ls1 += lq1[i] * lk1[i]; ls2 += lq2[i] * lk2[i]; }
    const float lam = __expf(ls1) - __expf(ls2) + 0.8f;

    const size_t HS = (size_t)SEQ * HDIM;
    const char* q1p = (const char*)(qkv + ((size_t)((0 * BATCH + b) * NHEAD + h)) * HS);
    const char* q2p = (const char*)(qkv + ((size_t)((1 * BATCH + b) * NHEAD + h)) * HS);
    const char* k1p = (const char*)(qkv + ((size_t)((2 * BATCH + b) * NHEAD + h)) * HS);
    const char* k2p = (const char*)(qkv + ((size_t)((3 * BATCH + b) * NHEAD + h)) * HS);
    const char* vtp = (const char*)(qkv + ((size_t)((4 * BATCH + b) * NHEAD + h)) * HS);

    bf16x8 qf1[2], qf2[2];
#pragma unroll
    for (int ks = 0; ks < 2; ++ks) {
        qf1[ks] = *(const bf16x8*)(q1p + (size_t)(q0 + fr) * 128 + ks * 64 + g * 16);
        qf2[ks] = *(const bf16x8*)(q2p + (size_t)(q0 + fr) * 128 + ks * 64 + g * 16);
    }

    const f32x4 z4{0.f, 0.f, 0.f, 0.f};
    f32x4 o1[4], o2[4];
#pragma unroll
    for (int d = 0; d < 4; ++d) { o1[d] = z4; o2[d] = z4; }
    f32x4 l1v = z4, l2v = z4;
    float m1 = -1e30f, m2 = -1e30f;

    const int lrow8 = lane >> 3;
    const int scol  = ((lane & 7) ^ lrow8) << 4;
    const int xw    = (fr & 7) << 4;

    const char* K1s = SM;
    const char* K2s = SM + 8192;
    const char* Vts = SM + 16384;

    auto smax = [&](f32x4& s0, f32x4& s1, f32x4& s2, f32x4& s3,
                    float& mS, f32x4& lv, f32x4* o, unsigned* pw) {
        f32x4 t = __builtin_elementwise_max(
            __builtin_elementwise_max(s0, s1), __builtin_elementwise_max(s2, s3));
        float pm = fmaxf(fmaxf(t[0], t[1]), fmaxf(t[2], t[3]));
        pm = fmaxf(pm, __shfl_xor(pm, 16));
        pm = fmaxf(pm, __shfl_xor(pm, 32));
        if (!__all(pm <= mS + 8.f * LOG2E)) {   // defer-max
            float mn = fmaxf(mS, pm);
            float alpha = __builtin_amdgcn_exp2f(mS - mn);
            lv *= alpha;
#pragma unroll
            for (int d = 0; d < 4; ++d) o[d] *= alpha;
            mS = mn;
        }
#pragma unroll
        for (int r = 0; r < 4; ++r) {
            s0[r] = __builtin_amdgcn_exp2f(s0[r] - mS);
            s1[r] = __builtin_amdgcn_exp2f(s1[r] - mS);
            s2[r] = __builtin_amdgcn_exp2f(s2[r] - mS);
            s3[r] = __builtin_amdgcn_exp2f(s3[r] - mS);
        }
        lv += (s0 + s1) + (s2 + s3);
        pw[0] = pkbf(s0[0], s0[1]); pw[1] = pkbf(s0[2], s0[3]);
        pw[2] = pkbf(s1[0], s1[1]); pw[3] = pkbf(s1[2], s1[3]);
        pw[4] = pkbf(s2[0], s2[1]); pw[5] = pkbf(s2[2], s2[3]);
        pw[6] = pkbf(s3[0], s3[1]); pw[7] = pkbf(s3[2], s3[3]);
    };

#define KRD(Ks, n, ks) (*(const bf16x8*)((Ks) + ((n) * 16 + fr) * 128 + (((ks) * 64 + g * 16) ^ xw)))

    for (int kt = 0; kt < SEQ / 64; ++kt) {
        const int kvb = kt * 64;
        __syncthreads();                        // everyone done reading SM
        // stage 24 chunks of 1024B (K1:0-7, K2:8-15, V:16-23); wave takes 6
#pragma unroll
        for (int i = 0; i < 6; ++i) {
            const int c = wave * 6 + i;
            const int t = c >> 3, ch = c & 7;
            const int row = ch * 8 + lrow8;
            char* ldst = SM + t * 8192 + ch * 1024;
            const char* src;
            if (t == 0)      src = k1p + (size_t)(kvb + row) * 128 + scol;
            else if (t == 1) src = k2p + (size_t)(kvb + row) * 128 + scol;
            else             src = vtp + (size_t)row * (SEQ * 2) + (size_t)kvb * 2 + scol;
            gload16(src, ldst);
        }
        __syncthreads();                        // vmcnt(0) drain: LDS ready

        // ---- QK state 1 ----
        f32x4 s10, s11, s12, s13;
        __builtin_amdgcn_s_setprio(1);
        s10 = MFMA16(KRD(K1s, 0, 0), qf1[0], z4);
        s11 = MFMA16(KRD(K1s, 1, 0), qf1[0], z4);
        s12 = MFMA16(KRD(K1s, 2, 0), qf1[0], z4);
        s13 = MFMA16(KRD(K1s, 3, 0), qf1[0], z4);
        s10 = MFMA16(KRD(K1s, 0, 1), qf1[1], s10);
        s11 = MFMA16(KRD(K1s, 1, 1), qf1[1], s11);
        s12 = MFMA16(KRD(K1s, 2, 1), qf1[1], s12);
        s13 = MFMA16(KRD(K1s, 3, 1), qf1[1], s13);
        __builtin_amdgcn_s_setprio(0);
        unsigned p1w[8];
        smax(s10, s11, s12, s13, m1, l1v, o1, p1w);

        // ---- QK state 2 (MFMAs overlap state-1 softmax VALU) ----
        f32x4 s20, s21, s22, s23;
        __builtin_amdgcn_s_setprio(1);
        s20 = MFMA16(KRD(K2s, 0, 0), qf2[0], z4);
        s21 = MFMA16(KRD(K2s, 1, 0), qf2[0], z4);
        s22 = MFMA16(KRD(K2s, 2, 0), qf2[0], z4);
        s23 = MFMA16(KRD(K2s, 3, 0), qf2[0], z4);
        s20 = MFMA16(KRD(K2s, 0, 1), qf2[1], s20);
        s21 = MFMA16(KRD(K2s, 1, 1), qf2[1], s21);
        s22 = MFMA16(KRD(K2s, 2, 1), qf2[1], s22);
        s23 = MFMA16(KRD(K2s, 3, 1), qf2[1], s23);
        __builtin_amdgcn_s_setprio(0);
        unsigned p2w[8];
        smax(s20, s21, s22, s23, m2, l2v, o2, p2w);

        // ---- PV, both states (shared V fragments) ----
        __builtin_amdgcn_s_setprio(1);
#pragma unroll
        for (int G = 0; G < 2; ++G) {
            union { unsigned u[4]; bf16x8 v; } pf1, pf2;
#pragma unroll
            for (int w = 0; w < 4; ++w) { pf1.u[w] = p1w[G * 4 + w]; pf2.u[w] = p2w[G * 4 + w]; }
#pragma unroll
            for (int ds = 0; ds < 4; ++ds) {
                const int vrow = ds * 16 + fr;
                bf16x8 vf = *(const bf16x8*)(Vts + vrow * 128 +
                              ((G * 64 + g * 16) ^ ((vrow & 7) << 4)));
                o1[ds] = MFMA16(vf, pf1.v, o1[ds]);
                o2[ds] = MFMA16(vf, pf2.v, o2[ds]);
            }
        }
        __builtin_amdgcn_s_setprio(0);
    }
#undef KRD

    float l1 = (l1v[0] + l1v[1]) + (l1v[2] + l1v[3]);
    float l2 = (l2v[0] + l2v[1]) + (l2v[2] + l2v[3]);
    l1 += __shfl_xor(l1, 16); l1 += __shfl_xor(l1, 32);
    l2 += __shfl_xor(l2, 16); l2 += __shfl_xor(l2, 32);

    const float i1 = 1.f / l1;
    const float i2 = lam / l2;
    float* op = attn_out + ((size_t)(b * SEQ + q0 + fr)) * CDIM + h * HDIM;
#pragma unroll
    for (int ds = 0; ds < 4; ++ds) {
        float4 o;
        o.x = o1[ds][0] * i1 - i2 * o2[ds][0];
        o.y = o1[ds][1] * i1 - i2 * o2[ds][1];
        o.z = o1[ds][2] * i1 - i2 * o2[ds][2];
        o.w = o1[ds][3] * i1 - i2 * o2[ds][3];
        *(float4*)(op + ds * 16 + g * 4) = o;
    }
}

// ---------------------------------------------------------------------------
// RMSNorm over last dim (1024) + 0.2 scale, fp32 in -> bf16 out.
// ---------------------------------------------------------------------------
__global__ __launch_bounds__(256) void rmsnorm_bf16(
    const float* __restrict__ in, bf16* __restrict__ out)
{
    __shared__ float red[4];
    const int row = blockIdx.x, tid = threadIdx.x;
    const float4 v = ((const float4*)(in + (size_t)row * CDIM))[tid];
    float ss = v.x * v.x + v.y * v.y + v.z * v.z + v.w * v.w;
#pragma unroll
    for (int m = 1; m < 64; m <<= 1) ss += __shfl_xor(ss, m);
    if ((tid & 63) == 0) red[tid >> 6] = ss;
    __syncthreads();
    float tot = red[0] + red[1] + red[2] + red[3];
    float sc = rsqrtf(tot * (1.f / CDIM) + EPSV) * 0.2f;
    bf16x4 o;
    o[0] = (bf16)(v.x * sc); o[1] = (bf16)(v.y * sc);
    o[2] = (bf16)(v.z * sc); o[3] = (bf16)(v.w * sc);
    ((bf16x4*)(out + (size_t)row * CDIM))[tid] = o;
}

extern "C" void kernel_launch(void* const* d_in, const int* in_sizes, int n_in,
                              void* d_out, int out_size, void* d_ws, size_t ws_size,
                              hipStream_t stream)
{
    (void)in_sizes; (void)n_in; (void)out_size; (void)ws_size;
    const float* x      = (const float*)d_in[0];
    const float* qkv_w  = (const float*)d_in[1];
    const float* proj_w = (const float*)d_in[2];
    const float* proj_b = (const float*)d_in[3];
    const float* lq1    = (const float*)d_in[4];
    const float* lk1    = (const float*)d_in[5];
    const float* lq2    = (const float*)d_in[6];
    const float* lk2    = (const float*)d_in[7];
    float* out = (float*)d_out;

    char* ws = (char*)d_ws;
    bf16*  qkv_t    = (bf16*)ws;
    bf16*  attn_b   = (bf16*)ws;
    float* attn_out = (float*)(ws + (size_t)40 * 1024 * 1024);
    bf16*  x_b      = (bf16*)(ws + (size_t)40 * 1024 * 1024);
    bf16*  qkvw_b   = (bf16*)(ws + (size_t)56 * 1024 * 1024);
    bf16*  projw_b  = (bf16*)(ws + (size_t)66 * 1024 * 1024);

    dim3 blk(256);
    cvt_all<<<dim3(5120), blk, 0, stream>>>(x, x_b, qkv_w, qkvw_b, proj_w, projw_b);
    gemm_lds<0><<<dim3(QKV_F / 128, (BATCH * SEQ) / 128), blk, 0, stream>>>(
        x_b, qkvw_b, nullptr, qkv_t, nullptr, BATCH * SEQ, QKV_F, CDIM);
    diff_attn<<<dim3(BATCH * NHEAD, SEQ / 64), blk, 0, stream>>>(
        qkv_t, lq1, lk1, lq2, lk2, attn_out);
    rmsnorm_bf16<<<dim3(BATCH * SEQ), blk, 0, stream>>>(attn_out, attn_b);
    gemm_lds<1><<<dim3(CDIM / 128, (BATCH * SEQ) / 128), blk, 0, stream>>>(
        attn_b, projw_b, proj_b, nullptr, out, BATCH * SEQ, CDIM, CDIM);
}